// Round 1
// baseline (624.908 us; speedup 1.0000x reference)
//
#include <hip/hip_runtime.h>

// WindowAttention on gfx950: one wave (64 threads) per (window, head).
// M=N=64 tokens, K=hd=32. QK^T and PV via v_mfma_f32_16x16x32_f16.
// f16 chosen over bf16: p=exp(s) <= ~400 << 65504, and f16 eps 2^-11 gives
// ~4x margin vs the 2%-of-max absmax threshold.

typedef __attribute__((ext_vector_type(8))) _Float16 half8;
typedef __attribute__((ext_vector_type(4))) float f32x4;

#define WSZ 8
#define HGT 128
#define WID 128
#define HWSZ (HGT * WID)
#define CCH 256
#define NHEADS 8
#define HDIM 32
#define VP 72   // v_lds row stride (halves): 144B rows -> 16B-aligned b128 frag reads
#define PP 72   // p_lds row stride (halves)
#define OP 35   // o_lds row stride (floats): 35 coprime-ish -> 2-way on coalesced read

__global__ void __launch_bounds__(64) wattn_kernel(
    const float* __restrict__ qg, const float* __restrict__ kg,
    const float* __restrict__ vg, const float* __restrict__ btg,
    const int* __restrict__ shiftp, float* __restrict__ outg) {

  __shared__ _Float16 v_lds[32 * VP];                                   // 4608 B
  __shared__ __align__(16) union { _Float16 p[64 * PP]; float o[64 * OP]; } po; // 9216 B
  __shared__ float bias_lds[225];                                       // 900 B

  const int tid  = threadIdx.x;
  const int quad = tid >> 4;   // 0..3
  const int c16  = tid & 15;   // 0..15

  // grid: bid = ((b*NHEADS + head) * 256) + wh*16 + ww  (ww innermost -> L2/L3 line sharing)
  const int bid  = blockIdx.x;
  const int wh   = (bid >> 4) & 15;
  const int ww   = bid & 15;
  const int th   = bid >> 8;
  const int head = th & (NHEADS - 1);
  const int b    = th >> 3;

  const int sh = *shiftp;

  const int base = (b * CCH + head * HDIM) * HWSZ;
  const float* qb = qg + base;
  const float* kb = kg + base;
  const float* vb = vg + base;

  // stage bias table column for this head, pre-scaled by log2(e)
  for (int t = tid; t < 225; t += 64)
    bias_lds[t] = btg[t * NHEADS + head] * 1.44269504088896f;

  // ---- direct global->register fragment loads for Q (A-op) and K (B-op) ----
  // A[m][k]: m = lane&15 (+16*tr), k = quad*8 + j   (q read at rolled position)
  // B[k][n]: k = quad*8 + j, n = lane&15 (+16*tc)   (k read unrolled)
  int offk[4], offq[4];
#pragma unroll
  for (int t = 0; t < 4; ++t) {
    const int tok = t * 16 + c16;
    offk[t] = (wh * WSZ + (tok >> 3)) * WID + ww * WSZ + (tok & 7);
    offq[t] = ((wh * WSZ + (tok >> 3) + sh) & (HGT - 1)) * WID +
              ((ww * WSZ + (tok & 7) + sh) & (WID - 1));
  }
  float kf[4][8], qf[4][8];
#pragma unroll
  for (int j = 0; j < 8; ++j) {
    const float* kc = kb + (quad * 8 + j) * HWSZ;
    const float* qc = qb + (quad * 8 + j) * HWSZ;
#pragma unroll
    for (int t = 0; t < 4; ++t) { kf[t][j] = kc[offk[t]]; qf[t][j] = qc[offq[t]]; }
  }

  // ---- stage V into LDS [ch][key] (coalesced global, conflict-free writes) ----
  const int offv = (wh * WSZ + (tid >> 3)) * WID + ww * WSZ + (tid & 7);
#pragma unroll
  for (int cc = 0; cc < 32; ++cc)
    v_lds[cc * VP + tid] = (_Float16)vb[cc * HWSZ + offv];

  half8 aq[4], bk[4];
#pragma unroll
  for (int t = 0; t < 4; ++t)
#pragma unroll
    for (int j = 0; j < 8; ++j) {
      aq[t][j] = (_Float16)qf[t][j];
      bk[t][j] = (_Float16)kf[t][j];
    }

  // ---- QK^T: 4x4 tiles of 16x16, K=32 in one mfma each ----
  const f32x4 zero4 = {0.f, 0.f, 0.f, 0.f};
  f32x4 sc[4][4];
#pragma unroll
  for (int tr = 0; tr < 4; ++tr)
#pragma unroll
    for (int tc = 0; tc < 4; ++tc)
      sc[tr][tc] = __builtin_amdgcn_mfma_f32_16x16x32_f16(aq[tr], bk[tc], zero4, 0, 0, 0);

  // ---- softmax (no max-subtraction: |s| bounded ~6, fp32 exp safe) ----
  // C-layout: row = tr*16 + quad*4 + reg, col = tc*16 + c16.
  // Row reduction = 4 local tc values + shfl_xor{1,2,4,8} within the 16-lane group.
  const float scale2 = 0.17677669529663687f * 1.44269504088896f; // 1/sqrt(32) * log2(e)
  float rinv[4][4];
#pragma unroll
  for (int tr = 0; tr < 4; ++tr) {
#pragma unroll
    for (int reg = 0; reg < 4; ++reg) {
      const int row = tr * 16 + quad * 4 + reg;
      const int yi = row >> 3, xi = row & 7;
      float pv[4], s = 0.f;
#pragma unroll
      for (int tc = 0; tc < 4; ++tc) {
        const int col = tc * 16 + c16;
        const int idx = (yi - (col >> 3) + 7) * 15 + (xi - (col & 7) + 7);
        const float e =
            __builtin_amdgcn_exp2f(fmaf(sc[tr][tc][reg], scale2, bias_lds[idx]));
        pv[tc] = e; s += e;
      }
      s += __shfl_xor(s, 1); s += __shfl_xor(s, 2);
      s += __shfl_xor(s, 4); s += __shfl_xor(s, 8);
      rinv[tr][reg] = __builtin_amdgcn_rcpf(s);
#pragma unroll
      for (int tc = 0; tc < 4; ++tc)
        po.p[row * PP + tc * 16 + c16] = (_Float16)pv[tc];
    }
  }

  __syncthreads(); // P fully in LDS before A-frag gather (single wave: cheap)

  // ---- P (A-op) and V (B-op) fragments, then PV: 4x2 tiles, K=64 = 2 chunks ----
  half8 aP[4][2], bV[2][2];
#pragma unroll
  for (int mt = 0; mt < 4; ++mt)
#pragma unroll
    for (int kc2 = 0; kc2 < 2; ++kc2)
      aP[mt][kc2] = *(const half8*)&po.p[(mt * 16 + c16) * PP + kc2 * 32 + quad * 8];
#pragma unroll
  for (int kc2 = 0; kc2 < 2; ++kc2)
#pragma unroll
    for (int nt = 0; nt < 2; ++nt)
      bV[kc2][nt] = *(const half8*)&v_lds[(nt * 16 + c16) * VP + kc2 * 32 + quad * 8];

  f32x4 of[4][2];
#pragma unroll
  for (int mt = 0; mt < 4; ++mt)
#pragma unroll
    for (int nt = 0; nt < 2; ++nt) {
      of[mt][nt] = zero4;
#pragma unroll
      for (int kc2 = 0; kc2 < 2; ++kc2)
        of[mt][nt] = __builtin_amdgcn_mfma_f32_16x16x32_f16(aP[mt][kc2], bV[kc2][nt],
                                                            of[mt][nt], 0, 0, 0);
    }

  __syncthreads(); // P reads done; safe to alias po.o over po.p

  // epilogue: normalize rows (same lane holds the same rows as the softmax step)
  // and transpose through LDS so global stores are channel-major coalesced
#pragma unroll
  for (int mt = 0; mt < 4; ++mt)
#pragma unroll
    for (int nt = 0; nt < 2; ++nt)
#pragma unroll
      for (int reg = 0; reg < 4; ++reg)
        po.o[(mt * 16 + quad * 4 + reg) * OP + nt * 16 + c16] =
            of[mt][nt][reg] * rinv[mt][reg];

  __syncthreads();

  // store at rolled position (output roll(+sh) == where q was read)
  const int hq = (wh * WSZ + (tid >> 3) + sh) & (HGT - 1);
  const int wq = (ww * WSZ + (tid & 7) + sh) & (WID - 1);
  float* ob = outg + base + hq * WID + wq;
#pragma unroll
  for (int c2 = 0; c2 < 32; ++c2)
    ob[c2 * HWSZ] = po.o[tid * OP + c2];
}

extern "C" void kernel_launch(void* const* d_in, const int* in_sizes, int n_in,
                              void* d_out, int out_size, void* d_ws, size_t ws_size,
                              hipStream_t stream) {
  const float* q  = (const float*)d_in[0];
  const float* k  = (const float*)d_in[1];
  const float* v  = (const float*)d_in[2];
  const float* bt = (const float*)d_in[3];
  const int*   sh = (const int*)d_in[4];
  float* out = (float*)d_out;

  // B(8) * HEADS(8) * 256 windows = 16384 blocks of 64 threads (one wave each)
  dim3 grid(16384), block(64);
  hipLaunchKernelGGL(wattn_kernel, grid, block, 0, stream, q, k, v, bt, sh, out);
}

// Round 3
// 483.818 us; speedup vs baseline: 1.2916x; 1.2916x over previous
//
#include <hip/hip_runtime.h>

// WindowAttention, R3 (= R2 + compile fix): 4 col-adjacent windows per
// 256-thread block (1 wave each, same b/head/wh). Transposed formulation
// S^T = K·Q^T so the P^T -> B-operand transform is pure cross-quad shuffles
// (no P LDS buffer, no barriers). GEMM2: O^T = V^T · P^T, V^T in LDS [ch][key].

typedef __attribute__((ext_vector_type(8))) _Float16 half8;
typedef __attribute__((ext_vector_type(2))) __fp16 fp16x2;  // cvt_pkrtz return type
typedef __attribute__((ext_vector_type(4))) float f32x4;
typedef unsigned int u32;

#define WSZ 8
#define HGT 128
#define WID 128
#define HWSZ (HGT * WID)
#define CCH 256
#define NHEADS 8
#define HDIM 32
#define VP 72   // v row stride in halves: 144B rows, 16B-aligned b128 frag reads

union WaveBuf {
  _Float16 v[32 * VP + 8];  // 4624 B (+8 halves: staggers bank phase across waves)
  float o[64 * 17];         // 4352 B output-transpose buffer (aliases dead V)
};

__device__ __forceinline__ void lds_fence() {
  asm volatile("s_waitcnt lgkmcnt(0)" ::: "memory");
}
__device__ __forceinline__ u32 h2u(fp16x2 h) {
  union { fp16x2 h; u32 u; } c; c.h = h; return c.u;
}

__global__ void __launch_bounds__(256, 4) wattn_kernel(
    const float* __restrict__ qg, const float* __restrict__ kg,
    const float* __restrict__ vg, const float* __restrict__ btg,
    const int* __restrict__ shiftp, float* __restrict__ outg) {

  __shared__ WaveBuf wb[4];
  __shared__ float bias_lds[226];

  const int tid  = threadIdx.x;
  const int wave = tid >> 6;
  const int lane = tid & 63;
  const int quad = lane >> 4;
  const int c16  = lane & 15;

  // grid: bid = ((b*8 + head)*16 + wh)*4 + wg ; block owns ww = wg*4 + {0..3}
  const int bid  = blockIdx.x;
  const int wg   = bid & 3;
  const int wh   = (bid >> 2) & 15;
  const int th   = bid >> 6;
  const int head = th & (NHEADS - 1);
  const int b    = th >> 3;
  const int ww   = wg * 4 + wave;

  const int sh   = *shiftp;
  const int base = (b * CCH + head * HDIM) * HWSZ;

  // bias table for this head (shared across the 4 waves), pre-scaled by log2(e)
  for (int t = tid; t < 225; t += 256)
    bias_lds[t] = btg[t * NHEADS + head] * 1.44269504088896f;

  // ---- per-wave direct fragment loads: K -> A-op (rows=key, unrolled pos),
  //      Q -> B-op (cols=query, rolled pos). ch = quad*8 + j. ----
  int offk[4], offq[4];
#pragma unroll
  for (int t = 0; t < 4; ++t) {
    const int tok = t * 16 + c16;
    offk[t] = (wh * WSZ + (tok >> 3)) * WID + ww * WSZ + (tok & 7);
    offq[t] = ((wh * WSZ + (tok >> 3) + sh) & (HGT - 1)) * WID +
              ((ww * WSZ + (tok & 7) + sh) & (WID - 1));
  }
  float kf[4][8], qf[4][8];
#pragma unroll
  for (int j = 0; j < 8; ++j) {
    const float* kc = kg + base + (quad * 8 + j) * HWSZ;
    const float* qc = qg + base + (quad * 8 + j) * HWSZ;
#pragma unroll
    for (int t = 0; t < 4; ++t) { kf[t][j] = kc[offk[t]]; qf[t][j] = qc[offq[t]]; }
  }

  // ---- cooperative V staging: 4 windows x 32ch x 8rows x 32cols,
  //      float4 loads = full 128B lines, f16 packed into per-wave [ch][key] ----
  {
    const float* vb = vg + base + (wh * WSZ) * WID + wg * 32;
#pragma unroll
    for (int i = 0; i < 8; ++i) {
      const int flat = i * 256 + tid;     // 0..2047
      const int col4 = flat & 7;
      const int row  = (flat >> 3) & 7;
      const int ch   = flat >> 6;
      const f32x4 f = *(const f32x4*)(vb + ch * HWSZ + row * WID + col4 * 4);
      const int w  = col4 >> 1;                  // target window within group
      const int kb = row * 8 + (col4 & 1) * 4;   // key index of first of 4 cols
      uint2 u;
      u.x = h2u(__builtin_amdgcn_cvt_pkrtz(f.x, f.y));
      u.y = h2u(__builtin_amdgcn_cvt_pkrtz(f.z, f.w));
      *(uint2*)&wb[w].v[ch * VP + kb] = u;
    }
  }

  __syncthreads();  // the only block-wide barrier

  half8 aK[4], bQ[4];
#pragma unroll
  for (int t = 0; t < 4; ++t)
#pragma unroll
    for (int j = 0; j < 8; ++j) {
      aK[t][j] = (_Float16)kf[t][j];
      bQ[t][j] = (_Float16)qf[t][j];
    }

  const f32x4 zero4 = {0.f, 0.f, 0.f, 0.f};
  const float scale2 = 0.17677669529663687f * 1.44269504088896f; // rsqrt(32)*log2e

  // bias row offsets for this lane's keys: r = tr*16 + quad*4 + reg
  int tsub[4];
#pragma unroll
  for (int reg = 0; reg < 4; ++reg) {
    const int t = quad * 4 + reg;
    tsub[reg] = (t >> 3) * 15 + (t & 7);
  }

  u32 pk01[4][4], pk23[4][4];  // [tr][tc]: packed f16 pairs of exp(S^T) regs {0,1},{2,3}
  float rinv[4];

  // ---- GEMM1 streamed per query tile tc: S^T col-tile -> softmax col-sum -> pack ----
#pragma unroll
  for (int tc = 0; tc < 4; ++tc) {
    f32x4 sc[4];
#pragma unroll
    for (int tr = 0; tr < 4; ++tr)
      sc[tr] = __builtin_amdgcn_mfma_f32_16x16x32_f16(aK[tr], bQ[tc], zero4, 0, 0, 0);
    const int q64 = tc * 16 + c16;
    const int qb  = ((q64 >> 3) + 7) * 15 + (q64 & 7) + 7;
    float e[4][4], s = 0.f;
#pragma unroll
    for (int tr = 0; tr < 4; ++tr)
#pragma unroll
      for (int reg = 0; reg < 4; ++reg) {
        const float ev = __builtin_amdgcn_exp2f(
            fmaf(sc[tr][reg], scale2, bias_lds[qb - tr * 30 - tsub[reg]]));
        e[tr][reg] = ev; s += ev;
      }
    // column sum: lane covers 16 keys; quads hold disjoint key quartets
    s += __shfl_xor(s, 16); s += __shfl_xor(s, 32);
    rinv[tc] = __builtin_amdgcn_rcpf(s);
#pragma unroll
    for (int tr = 0; tr < 4; ++tr) {
      pk01[tr][tc] = h2u(__builtin_amdgcn_cvt_pkrtz(e[tr][0], e[tr][1]));
      pk23[tr][tc] = h2u(__builtin_amdgcn_cvt_pkrtz(e[tr][2], e[tr][3]));
    }
  }

  // ---- GEMM2: O^T[ch][q] = V^T (A, LDS) x P^T (B, cross-quad shuffles) ----
  half8 aV[2][2];
#pragma unroll
  for (int mt = 0; mt < 2; ++mt)
#pragma unroll
    for (int kc = 0; kc < 2; ++kc)
      aV[mt][kc] = *(const half8*)&wb[wave].v[(mt * 16 + c16) * VP + kc * 32 + quad * 8];

  // B-frag element j needs pexp[tr=kc*2+(quad>>1)][nt][reg=j&3] from lane
  // (2*(quad&1)+(j>>2))*16 + c16 : same c16, compile-time reg -> shfl + select.
  const int s0 = ((lane & 16) << 1) | c16;
  const int s1 = s0 + 16;
  const bool hi = (lane & 32) != 0;

  f32x4 of2[2][4];
#pragma unroll
  for (int mt = 0; mt < 2; ++mt)
#pragma unroll
    for (int nt = 0; nt < 4; ++nt) of2[mt][nt] = zero4;

#pragma unroll
  for (int nt = 0; nt < 4; ++nt)
#pragma unroll
    for (int kc = 0; kc < 2; ++kc) {
      const int t0 = kc * 2, t1 = kc * 2 + 1;
      const u32 w0a = __shfl(pk01[t0][nt], s0), w0b = __shfl(pk01[t1][nt], s0);
      const u32 w1a = __shfl(pk23[t0][nt], s0), w1b = __shfl(pk23[t1][nt], s0);
      const u32 w2a = __shfl(pk01[t0][nt], s1), w2b = __shfl(pk01[t1][nt], s1);
      const u32 w3a = __shfl(pk23[t0][nt], s1), w3b = __shfl(pk23[t1][nt], s1);
      union { u32 u[4]; half8 h; } bp;
      bp.u[0] = hi ? w0b : w0a;
      bp.u[1] = hi ? w1b : w1a;
      bp.u[2] = hi ? w2b : w2a;
      bp.u[3] = hi ? w3b : w3a;
#pragma unroll
      for (int mt = 0; mt < 2; ++mt)
        of2[mt][nt] = __builtin_amdgcn_mfma_f32_16x16x32_f16(aV[mt][kc], bp.h,
                                                             of2[mt][nt], 0, 0, 0);
    }

  // ---- epilogue: normalize by rinv[query col], transpose via per-wave LDS
  //      (aliases dead V buffer; wave-local fences only), coalesced stores ----
  const int hq = (wh * WSZ + (lane >> 3) + sh) & (HGT - 1);
  const int wq = (ww * WSZ + (lane & 7) + sh) & (WID - 1);
  float* ob = outg + base + hq * WID + wq;
  float* obuf = wb[wave].o;

#pragma unroll
  for (int mt = 0; mt < 2; ++mt) {
    lds_fence();
#pragma unroll
    for (int nt = 0; nt < 4; ++nt)
#pragma unroll
      for (int reg = 0; reg < 4; ++reg)
        obuf[(nt * 16 + c16) * 17 + quad * 4 + reg] = of2[mt][nt][reg] * rinv[nt];
    lds_fence();
#pragma unroll
    for (int c = 0; c < 16; ++c)
      ob[(mt * 16 + c) * HWSZ] = obuf[lane * 17 + c];
  }
}

extern "C" void kernel_launch(void* const* d_in, const int* in_sizes, int n_in,
                              void* d_out, int out_size, void* d_ws, size_t ws_size,
                              hipStream_t stream) {
  const float* q  = (const float*)d_in[0];
  const float* k  = (const float*)d_in[1];
  const float* v  = (const float*)d_in[2];
  const float* bt = (const float*)d_in[3];
  const int*   sh = (const int*)d_in[4];
  float* out = (float*)d_out;

  // 8b x 8heads x 16wh x 4 window-groups = 4096 blocks x 256 threads
  dim3 grid(4096), block(256);
  hipLaunchKernelGGL(wattn_kernel, grid, block, 0, stream, q, k, v, bt, sh, out);
}